// Round 1
// baseline (172.775 us; speedup 1.0000x reference)
//
#include <hip/hip_runtime.h>
#include <hip/hip_bf16.h>

// Problem constants
#define NPTS   3000
#define MPTS   3000
#define KNODES 6000
#define HEADS  4
#define HID    64
#define FDIM   256      // HEADS*HID
#define OUTC   2
#define R2     0.0025f
#define NSLOPE 0.2f
#define MAXNBR 64

// ---------------- workspace layout (floats) ----------------
// ptsx[6000] ptsy[6000] ptsz[6000] sq[6000] es[24000] ed[24000]
// bufA[1536000] bufB[1536000]  then ints: nbr_cnt[6000], nbr_idx[6000*64]
#define OFF_PX   0
#define OFF_PY   6000
#define OFF_PZ   12000
#define OFF_SQ   18000
#define OFF_ES   24000
#define OFF_ED   48000
#define OFF_A    72000
#define OFF_B    1608000
#define OFF_END  3144000          // floats
// int region starts at byte 4*OFF_END

// Build pts SoA (concat pos | pos_non_manifold, transposed) + per-point sq.
// Replicates reference: sq = x*x + y*y + z*z in fp32, left-to-right, no fma.
__global__ void k_pts(const float* __restrict__ pos, const float* __restrict__ pnm,
                      float* __restrict__ px, float* __restrict__ py,
                      float* __restrict__ pz, float* __restrict__ sq) {
    int i = blockIdx.x * 256 + threadIdx.x;
    if (i >= KNODES) return;
    float x, y, z;
    if (i < NPTS) {
        x = pos[0 * NPTS + i]; y = pos[1 * NPTS + i]; z = pos[2 * NPTS + i];
    } else {
        int q = i - NPTS;
        x = pnm[0 * MPTS + q]; y = pnm[1 * MPTS + q]; z = pnm[2 * MPTS + q];
    }
    px[i] = x; py[i] = y; pz[i] = z;
    sq[i] = __fadd_rn(__fadd_rn(__fmul_rn(x, x), __fmul_rn(y, y)), __fmul_rn(z, z));
}

// Neighbor lists via gram-trick d2 = sq_i + sq_j - 2*dot (exact fp32 ops, no
// contraction) to match the reference mask bit-for-bit where possible.
// 4 rows per block to amortize the j-scan's L2 traffic.
__global__ void k_nbr(const float* __restrict__ px, const float* __restrict__ py,
                      const float* __restrict__ pz, const float* __restrict__ sq,
                      int* __restrict__ cnt, int* __restrict__ idx) {
    __shared__ int s_cnt[4];
    __shared__ int s_idx[4][MAXNBR];
    int t = threadIdx.x;
    int i0 = blockIdx.x * 4;
    if (t < 4) s_cnt[t] = 0;
    __syncthreads();
    float xi[4], yi[4], zi[4], si[4];
#pragma unroll
    for (int r = 0; r < 4; ++r) {
        xi[r] = px[i0 + r]; yi[r] = py[i0 + r]; zi[r] = pz[i0 + r]; si[r] = sq[i0 + r];
    }
    for (int j = t; j < KNODES; j += 256) {
        float xj = px[j], yj = py[j], zj = pz[j], sj = sq[j];
#pragma unroll
        for (int r = 0; r < 4; ++r) {
            float dot = __fadd_rn(__fadd_rn(__fmul_rn(xi[r], xj), __fmul_rn(yi[r], yj)),
                                  __fmul_rn(zi[r], zj));
            float d2 = __fsub_rn(__fadd_rn(si[r], sj), __fmul_rn(2.0f, dot));
            if (d2 < R2) {
                int p = atomicAdd(&s_cnt[r], 1);
                if (p < MAXNBR) s_idx[r][p] = j;
            }
        }
    }
    __syncthreads();
    if (t < 4) cnt[i0 + t] = min(s_cnt[t], MAXNBR);
#pragma unroll
    for (int r = 0; r < 4; ++r) {
        int c = min(s_cnt[r], MAXNBR);
        if (t < c) idx[(i0 + r) * MAXNBR + t] = s_idx[r][t];
    }
}

// Layer-1 transform: h = pts @ W1  ([K,3] x [3,256])
__global__ void k_h1(const float* __restrict__ px, const float* __restrict__ py,
                     const float* __restrict__ pz, const float* __restrict__ W1,
                     float* __restrict__ h) {
    int i = blockIdx.x, f = threadIdx.x;
    h[i * FDIM + f] = fmaf(px[i], W1[f],
                      fmaf(py[i], W1[FDIM + f],
                           pz[i] * W1[2 * FDIM + f]));
}

// Per-head src/dst scores. One wave per head (HID==64 lanes). 256 thr/node.
__global__ void k_scores(const float* __restrict__ h, const float* __restrict__ asrc,
                         const float* __restrict__ adst, float* __restrict__ es,
                         float* __restrict__ ed) {
    int i = blockIdx.x, t = threadIdx.x;
    float v = h[i * FDIM + t];
    float s = v * asrc[t];
    float d = v * adst[t];
    for (int off = 32; off; off >>= 1) {
        s += __shfl_down(s, off, 64);
        d += __shfl_down(d, off, 64);
    }
    if ((t & 63) == 0) {
        es[i * HEADS + (t >> 6)] = s;
        ed[i * HEADS + (t >> 6)] = d;
    }
}

// Sparse softmax-aggregate + bias + relu. One block (256 thr) per node.
__global__ void k_agg(const float* __restrict__ h, const float* __restrict__ es,
                      const float* __restrict__ ed, const int* __restrict__ cnt,
                      const int* __restrict__ idx, const float* __restrict__ bias,
                      float* __restrict__ out) {
    __shared__ int   s_idx[MAXNBR];
    __shared__ float s_e[MAXNBR * HEADS];
    __shared__ float s_ed[HEADS];
    int i = blockIdx.x, t = threadIdx.x;
    int c = cnt[i];
    if (t < c) s_idx[t] = idx[i * MAXNBR + t];
    if (t < HEADS) s_ed[t] = ed[i * HEADS + t];
    __syncthreads();
    if (t < c * HEADS) {
        int jl = t >> 2, hh = t & 3;
        float e = s_ed[hh] + es[s_idx[jl] * HEADS + hh];
        e = (e >= 0.f) ? e : NSLOPE * e;
        s_e[jl * HEADS + hh] = e;
    }
    __syncthreads();
    int hh = t >> 6;
    float m = -1e30f;
    for (int jl = 0; jl < c; ++jl) m = fmaxf(m, s_e[jl * HEADS + hh]);
    float ssum = 0.f, acc = 0.f;
    for (int jl = 0; jl < c; ++jl) {
        float p = __expf(s_e[jl * HEADS + hh] - m);
        ssum += p;
        acc = fmaf(p, h[s_idx[jl] * FDIM + t], acc);
    }
    float o = acc / ssum + bias[t];
    out[i * FDIM + t] = fmaxf(o, 0.f);
}

// Layer-2 transform: h2 = x @ W2  ([K,256] x [256,256]).  16 rows per block,
// x-tile staged in LDS (broadcast reads), W2 columns served from L2 (256 KB).
#define GROWS 16
__global__ void k_gemm2(const float* __restrict__ x, const float* __restrict__ W,
                        float* __restrict__ out) {
    __shared__ __align__(16) float xs[GROWS * FDIM];
    int t = threadIdx.x;
    int r0 = blockIdx.x * GROWS;
    for (int q = t; q < GROWS * FDIM; q += 256) xs[q] = x[r0 * FDIM + q];
    __syncthreads();
    float acc[GROWS];
#pragma unroll
    for (int r = 0; r < GROWS; ++r) acc[r] = 0.f;
    const int f = t;
    for (int k4 = 0; k4 < FDIM / 4; ++k4) {
        int k = k4 * 4;
        float w0 = W[(k + 0) * FDIM + f];
        float w1 = W[(k + 1) * FDIM + f];
        float w2 = W[(k + 2) * FDIM + f];
        float w3 = W[(k + 3) * FDIM + f];
#pragma unroll
        for (int r = 0; r < GROWS; ++r) {
            float4 xv = *reinterpret_cast<const float4*>(&xs[r * FDIM + k]);
            acc[r] = fmaf(xv.x, w0, fmaf(xv.y, w1, fmaf(xv.z, w2, fmaf(xv.w, w3, acc[r]))));
        }
    }
#pragma unroll
    for (int r = 0; r < GROWS; ++r) out[(r0 + r) * FDIM + f] = acc[r];
}

// Final fc over nodes [M, K). One wave per node; out[(i-M)*2+o] flat.
__global__ void k_fc(const float* __restrict__ x, const float* __restrict__ fw,
                     const float* __restrict__ fb, float* __restrict__ out) {
    int t = threadIdx.x;
    int wv = t >> 6, lane = t & 63;
    int q = blockIdx.x * 4 + wv;          // 0..2999
    int i = MPTS + q;
    float p0 = 0.f, p1 = 0.f;
    for (int k = lane; k < FDIM; k += 64) {
        float v = x[i * FDIM + k];
        p0 = fmaf(v, fw[k * OUTC + 0], p0);
        p1 = fmaf(v, fw[k * OUTC + 1], p1);
    }
    for (int off = 32; off; off >>= 1) {
        p0 += __shfl_down(p0, off, 64);
        p1 += __shfl_down(p1, off, 64);
    }
    if (lane == 0) {
        out[q * OUTC + 0] = p0 + fb[0];
        out[q * OUTC + 1] = p1 + fb[1];
    }
}

extern "C" void kernel_launch(void* const* d_in, const int* in_sizes, int n_in,
                              void* d_out, int out_size, void* d_ws, size_t ws_size,
                              hipStream_t stream) {
    const float* pos   = (const float*)d_in[0];
    const float* pnm   = (const float*)d_in[1];
    const float* W1    = (const float*)d_in[2];
    const float* asrc1 = (const float*)d_in[3];
    const float* adst1 = (const float*)d_in[4];
    const float* b1    = (const float*)d_in[5];
    const float* W2    = (const float*)d_in[6];
    const float* asrc2 = (const float*)d_in[7];
    const float* adst2 = (const float*)d_in[8];
    const float* b2    = (const float*)d_in[9];
    const float* fcw   = (const float*)d_in[10];
    const float* fcb   = (const float*)d_in[11];
    float* out = (float*)d_out;

    float* w   = (float*)d_ws;
    float* px  = w + OFF_PX;
    float* py  = w + OFF_PY;
    float* pz  = w + OFF_PZ;
    float* sq  = w + OFF_SQ;
    float* es  = w + OFF_ES;
    float* ed  = w + OFF_ED;
    float* bufA = w + OFF_A;
    float* bufB = w + OFF_B;
    int* nbr_cnt = (int*)((char*)d_ws + (size_t)4 * OFF_END);
    int* nbr_idx = nbr_cnt + KNODES;

    k_pts<<<(KNODES + 255) / 256, 256, 0, stream>>>(pos, pnm, px, py, pz, sq);
    k_nbr<<<KNODES / 4, 256, 0, stream>>>(px, py, pz, sq, nbr_cnt, nbr_idx);

    // Layer 1
    k_h1<<<KNODES, FDIM, 0, stream>>>(px, py, pz, W1, bufB);
    k_scores<<<KNODES, FDIM, 0, stream>>>(bufB, asrc1, adst1, es, ed);
    k_agg<<<KNODES, FDIM, 0, stream>>>(bufB, es, ed, nbr_cnt, nbr_idx, b1, bufA);

    // Layer 2
    k_gemm2<<<KNODES / GROWS, FDIM, 0, stream>>>(bufA, W2, bufB);
    k_scores<<<KNODES, FDIM, 0, stream>>>(bufB, asrc2, adst2, es, ed);
    k_agg<<<KNODES, FDIM, 0, stream>>>(bufB, es, ed, nbr_cnt, nbr_idx, b2, bufA);

    // FC + flat-reshape output
    k_fc<<<MPTS / 4, 256, 0, stream>>>(bufA, fcw, fcb, out);
}

// Round 2
// 150.419 us; speedup vs baseline: 1.1486x; 1.1486x over previous
//
#include <hip/hip_runtime.h>
#include <hip/hip_bf16.h>

// Problem constants
#define NPTS   3000
#define MPTS   3000
#define KNODES 6000
#define HEADS  4
#define HID    64
#define FDIM   256      // HEADS*HID
#define OUTC   2
#define R2     0.0025f
#define NSLOPE 0.2f
#define MAXNBR 64

// ---------------- workspace layout (floats) ----------------
#define OFF_PX   0
#define OFF_PY   6000
#define OFF_PZ   12000
#define OFF_SQ   18000
#define OFF_ES   24000
#define OFF_ED   48000
#define OFF_A    72000        // x (layer-1 output / gemm2 input), 6000*256
#define OFF_B    1608000      // h (layer transform output), 6000*256
#define OFF_END  3144000      // floats; int region starts at byte 4*OFF_END

// Fused: pts SoA + sq (exact fp32 ops, matches reference bitwise) + layer-1
// transform h1 = pts@W1 + per-head src/dst scores. One block per node.
__global__ void k_ptsh1s(const float* __restrict__ pos, const float* __restrict__ pnm,
                         float* __restrict__ px, float* __restrict__ py,
                         float* __restrict__ pz, float* __restrict__ sq,
                         const float* __restrict__ W1, const float* __restrict__ asrc,
                         const float* __restrict__ adst, float* __restrict__ h,
                         float* __restrict__ es, float* __restrict__ ed) {
    int i = blockIdx.x, t = threadIdx.x;
    float x, y, z;
    if (i < NPTS) {
        x = pos[i]; y = pos[NPTS + i]; z = pos[2 * NPTS + i];
    } else {
        int q = i - NPTS;
        x = pnm[q]; y = pnm[MPTS + q]; z = pnm[2 * MPTS + q];
    }
    if (t == 0) {
        px[i] = x; py[i] = y; pz[i] = z;
        sq[i] = __fadd_rn(__fadd_rn(__fmul_rn(x, x), __fmul_rn(y, y)), __fmul_rn(z, z));
    }
    float hv = fmaf(x, W1[t], fmaf(y, W1[FDIM + t], z * W1[2 * FDIM + t]));
    h[i * FDIM + t] = hv;
    float s = hv * asrc[t];
    float d = hv * adst[t];
    for (int off = 32; off; off >>= 1) {
        s += __shfl_down(s, off, 64);
        d += __shfl_down(d, off, 64);
    }
    if ((t & 63) == 0) {
        es[i * HEADS + (t >> 6)] = s;
        ed[i * HEADS + (t >> 6)] = d;
    }
}

// Neighbor lists via gram-trick d2 = sq_i + sq_j - 2*dot (exact fp32 ops, no
// contraction) to match the reference mask bit-for-bit where possible.
__global__ void k_nbr(const float* __restrict__ px, const float* __restrict__ py,
                      const float* __restrict__ pz, const float* __restrict__ sq,
                      int* __restrict__ cnt, int* __restrict__ idx) {
    __shared__ int s_cnt[4];
    __shared__ int s_idx[4][MAXNBR];
    int t = threadIdx.x;
    int i0 = blockIdx.x * 4;
    if (t < 4) s_cnt[t] = 0;
    __syncthreads();
    float xi[4], yi[4], zi[4], si[4];
#pragma unroll
    for (int r = 0; r < 4; ++r) {
        xi[r] = px[i0 + r]; yi[r] = py[i0 + r]; zi[r] = pz[i0 + r]; si[r] = sq[i0 + r];
    }
    for (int j = t; j < KNODES; j += 256) {
        float xj = px[j], yj = py[j], zj = pz[j], sj = sq[j];
#pragma unroll
        for (int r = 0; r < 4; ++r) {
            float dot = __fadd_rn(__fadd_rn(__fmul_rn(xi[r], xj), __fmul_rn(yi[r], yj)),
                                  __fmul_rn(zi[r], zj));
            float d2 = __fsub_rn(__fadd_rn(si[r], sj), __fmul_rn(2.0f, dot));
            if (d2 < R2) {
                int p = atomicAdd(&s_cnt[r], 1);
                if (p < MAXNBR) s_idx[r][p] = j;
            }
        }
    }
    __syncthreads();
    if (t < 4) cnt[i0 + t] = min(s_cnt[t], MAXNBR);
#pragma unroll
    for (int r = 0; r < 4; ++r) {
        int c = min(s_cnt[r], MAXNBR);
        if (t < c) idx[(i0 + r) * MAXNBR + t] = s_idx[r][t];
    }
}

// Sparse softmax-aggregate + bias + relu (layer 1). One block per node.
__global__ void k_agg(const float* __restrict__ h, const float* __restrict__ es,
                      const float* __restrict__ ed, const int* __restrict__ cnt,
                      const int* __restrict__ idx, const float* __restrict__ bias,
                      float* __restrict__ out) {
    __shared__ int   s_idx[MAXNBR];
    __shared__ float s_e[MAXNBR * HEADS];
    __shared__ float s_ed[HEADS];
    int i = blockIdx.x, t = threadIdx.x;
    int c = cnt[i];
    if (t < c) s_idx[t] = idx[i * MAXNBR + t];
    if (t < HEADS) s_ed[t] = ed[i * HEADS + t];
    __syncthreads();
    if (t < c * HEADS) {
        int jl = t >> 2, hh = t & 3;
        float e = s_ed[hh] + es[s_idx[jl] * HEADS + hh];
        e = (e >= 0.f) ? e : NSLOPE * e;
        s_e[jl * HEADS + hh] = e;
    }
    __syncthreads();
    int hh = t >> 6;
    float m = -1e30f;
    for (int jl = 0; jl < c; ++jl) m = fmaxf(m, s_e[jl * HEADS + hh]);
    float ssum = 0.f, acc = 0.f;
    for (int jl = 0; jl < c; ++jl) {
        float p = __expf(s_e[jl * HEADS + hh] - m);
        ssum += p;
        acc = fmaf(p, h[s_idx[jl] * FDIM + t], acc);
    }
    float o = acc / ssum + bias[t];
    out[i * FDIM + t] = fmaxf(o, 0.f);
}

// Layer-2 transform fused with scores: h2 = x @ W2 ([6000,256]x[256,256]),
// then es/ed per row per head. Block = 256 thr, 8 rows/block, grid 750.
// Thread layout: tl = t&127 handles cols (2tl, 2tl+1); half = t>>7 handles
// rows [half*4, half*4+4). W loads are float2 (coalesced 512B/wave/inst);
// x tile in LDS read as float4. FMA-issue-dominant inner loop.
#define G2ROWS 8
__global__ void k_gemm2s(const float* __restrict__ x, const float* __restrict__ W,
                         const float* __restrict__ asrc, const float* __restrict__ adst,
                         float* __restrict__ out, float* __restrict__ es,
                         float* __restrict__ ed) {
    __shared__ __align__(16) float xs[G2ROWS * FDIM];
    int t = threadIdx.x;
    int tl = t & 127, half = t >> 7;
    int r0 = blockIdx.x * G2ROWS;

    const float4* xg = reinterpret_cast<const float4*>(x + r0 * FDIM);
    float4* xs4 = reinterpret_cast<float4*>(xs);
#pragma unroll
    for (int q = 0; q < (G2ROWS * FDIM / 4) / 256; ++q)
        xs4[q * 256 + t] = xg[q * 256 + t];
    __syncthreads();

    float acc0[4], acc1[4];
#pragma unroll
    for (int r = 0; r < 4; ++r) { acc0[r] = 0.f; acc1[r] = 0.f; }

    const float2* W2p = reinterpret_cast<const float2*>(W);
    const int rbase = half * 4;
    for (int k4 = 0; k4 < FDIM / 4; ++k4) {
        int k = k4 * 4;
        float2 w0 = W2p[(k + 0) * 128 + tl];
        float2 w1 = W2p[(k + 1) * 128 + tl];
        float2 w2 = W2p[(k + 2) * 128 + tl];
        float2 w3 = W2p[(k + 3) * 128 + tl];
#pragma unroll
        for (int r = 0; r < 4; ++r) {
            float4 xv = xs4[(rbase + r) * 64 + k4];
            acc0[r] = fmaf(xv.x, w0.x, fmaf(xv.y, w1.x, fmaf(xv.z, w2.x, fmaf(xv.w, w3.x, acc0[r]))));
            acc1[r] = fmaf(xv.x, w0.y, fmaf(xv.y, w1.y, fmaf(xv.z, w2.y, fmaf(xv.w, w3.y, acc1[r]))));
        }
    }

    int f0 = 2 * tl, f1 = 2 * tl + 1;
    int head = tl >> 5;                      // = f0/64 = f1/64
    float as0 = asrc[f0], as1 = asrc[f1], ad0 = adst[f0], ad1 = adst[f1];
#pragma unroll
    for (int r = 0; r < 4; ++r) {
        int row = r0 + rbase + r;
        // store h2 (float2, coalesced)
        *reinterpret_cast<float2*>(&out[row * FDIM + f0]) = make_float2(acc0[r], acc1[r]);
        float s = fmaf(acc0[r], as0, acc1[r] * as1);
        float d = fmaf(acc0[r], ad0, acc1[r] * ad1);
        for (int off = 16; off; off >>= 1) {
            s += __shfl_down(s, off, 32);
            d += __shfl_down(d, off, 32);
        }
        if ((t & 31) == 0) {
            es[row * HEADS + head] = s;
            ed[row * HEADS + head] = d;
        }
    }
}

// Layer-2 aggregate + bias + relu + final fc, only for nodes >= MPTS.
// One block per output node; writes out[q*2 + {0,1}].
__global__ void k_agg2fc(const float* __restrict__ h, const float* __restrict__ es,
                         const float* __restrict__ ed, const int* __restrict__ cnt,
                         const int* __restrict__ idx, const float* __restrict__ bias,
                         const float* __restrict__ fw, const float* __restrict__ fb,
                         float* __restrict__ out) {
    __shared__ int   s_idx[MAXNBR];
    __shared__ float s_e[MAXNBR * HEADS];
    __shared__ float s_ed[HEADS];
    __shared__ float s_red[8];
    int q = blockIdx.x;
    int i = MPTS + q;
    int t = threadIdx.x;
    int c = cnt[i];
    if (t < c) s_idx[t] = idx[i * MAXNBR + t];
    if (t < HEADS) s_ed[t] = ed[i * HEADS + t];
    __syncthreads();
    if (t < c * HEADS) {
        int jl = t >> 2, hh = t & 3;
        float e = s_ed[hh] + es[s_idx[jl] * HEADS + hh];
        e = (e >= 0.f) ? e : NSLOPE * e;
        s_e[jl * HEADS + hh] = e;
    }
    __syncthreads();
    int hh = t >> 6;
    float m = -1e30f;
    for (int jl = 0; jl < c; ++jl) m = fmaxf(m, s_e[jl * HEADS + hh]);
    float ssum = 0.f, acc = 0.f;
    for (int jl = 0; jl < c; ++jl) {
        float p = __expf(s_e[jl * HEADS + hh] - m);
        ssum += p;
        acc = fmaf(p, h[s_idx[jl] * FDIM + t], acc);
    }
    float v = fmaxf(acc / ssum + bias[t], 0.f);
    float p0 = v * fw[t * OUTC + 0];
    float p1 = v * fw[t * OUTC + 1];
    for (int off = 32; off; off >>= 1) {
        p0 += __shfl_down(p0, off, 64);
        p1 += __shfl_down(p1, off, 64);
    }
    if ((t & 63) == 0) {
        s_red[(t >> 6) * 2 + 0] = p0;
        s_red[(t >> 6) * 2 + 1] = p1;
    }
    __syncthreads();
    if (t == 0) {
        float o0 = s_red[0] + s_red[2] + s_red[4] + s_red[6] + fb[0];
        float o1 = s_red[1] + s_red[3] + s_red[5] + s_red[7] + fb[1];
        out[q * OUTC + 0] = o0;
        out[q * OUTC + 1] = o1;
    }
}

extern "C" void kernel_launch(void* const* d_in, const int* in_sizes, int n_in,
                              void* d_out, int out_size, void* d_ws, size_t ws_size,
                              hipStream_t stream) {
    const float* pos   = (const float*)d_in[0];
    const float* pnm   = (const float*)d_in[1];
    const float* W1    = (const float*)d_in[2];
    const float* asrc1 = (const float*)d_in[3];
    const float* adst1 = (const float*)d_in[4];
    const float* b1    = (const float*)d_in[5];
    const float* W2    = (const float*)d_in[6];
    const float* asrc2 = (const float*)d_in[7];
    const float* adst2 = (const float*)d_in[8];
    const float* b2    = (const float*)d_in[9];
    const float* fcw   = (const float*)d_in[10];
    const float* fcb   = (const float*)d_in[11];
    float* out = (float*)d_out;

    float* w    = (float*)d_ws;
    float* px   = w + OFF_PX;
    float* py   = w + OFF_PY;
    float* pz   = w + OFF_PZ;
    float* sq   = w + OFF_SQ;
    float* es   = w + OFF_ES;
    float* ed   = w + OFF_ED;
    float* bufA = w + OFF_A;
    float* bufB = w + OFF_B;
    int* nbr_cnt = (int*)((char*)d_ws + (size_t)4 * OFF_END);
    int* nbr_idx = nbr_cnt + KNODES;

    // pts + layer-1 transform + scores (fused)
    k_ptsh1s<<<KNODES, FDIM, 0, stream>>>(pos, pnm, px, py, pz, sq,
                                          W1, asrc1, adst1, bufB, es, ed);
    // neighbor lists (needs px..sq only)
    k_nbr<<<KNODES / 4, 256, 0, stream>>>(px, py, pz, sq, nbr_cnt, nbr_idx);
    // layer-1 aggregate -> x
    k_agg<<<KNODES, FDIM, 0, stream>>>(bufB, es, ed, nbr_cnt, nbr_idx, b1, bufA);
    // layer-2 transform + scores (fused)
    k_gemm2s<<<KNODES / G2ROWS, 256, 0, stream>>>(bufA, W2, asrc2, adst2, bufB, es, ed);
    // layer-2 aggregate + fc, output nodes only
    k_agg2fc<<<MPTS, FDIM, 0, stream>>>(bufB, es, ed, nbr_cnt, nbr_idx, b2, fcw, fcb, out);
}